// Round 12
// baseline (101.064 us; speedup 1.0000x reference)
//
#include <hip/hip_runtime.h>
#include <hip/hip_fp16.h>

typedef __bf16 bf16x8 __attribute__((ext_vector_type(8)));
typedef float floatx16 __attribute__((ext_vector_type(16)));
typedef unsigned int uint;
typedef unsigned short ushort;
typedef uint  uintx4  __attribute__((ext_vector_type(4)));
typedef float floatx4 __attribute__((ext_vector_type(4)));

constexpr int Mdim = 256, Ndim = 8192, Kdim = 8192;
constexpr int BN = 256, KSPLIT = 8;
constexpr int KS = Kdim / KSPLIT;    // 1024 k per block
constexpr int NT = KS / 64;          // 16 64k-steps (1 per phase)
constexpr int KB = Kdim / 256;       // 32 superblocks per weight row

union U8 { uint u[4]; bf16x8 v; };

__device__ __forceinline__ uint cvtpk(float lo, float hi) {
  uint r; asm("v_cvt_pk_bf16_f32 %0, %1, %2" : "=v"(r) : "v"(lo), "v"(hi));
  return r;
}
template <typename T>
__device__ __forceinline__ T gld(const void* p) {
  return *(const __attribute__((address_space(1))) T*)p;
}
__device__ __forceinline__ void glds16(const void* g, void* l) {
  __builtin_amdgcn_global_load_lds(
      (const __attribute__((address_space(1))) uint*)g,
      (__attribute__((address_space(3))) uint*)l, 16, 0, 0);
}
// B LDS row: 8 chunks of 16B, XOR-swizzled (R6/R9-verified relationship)
__device__ __forceinline__ int bswz(int row, int ch) {
  return row * 64 + ((ch ^ (row & 7)) << 3);
}
#define WAITVM(n) asm volatile("s_waitcnt vmcnt(" #n ")" ::: "memory")

template<bool PRE>
__global__ __launch_bounds__(512, 2)
void q4k_gemm(const float* __restrict__ x, const bf16x8* __restrict__ xbf,
              const int* __restrict__ qw, const float* __restrict__ bias,
              float* __restrict__ out)
{
  __shared__ ushort Al[2][16384];   // A tile per step: 32 frags x 64 lanes x 16B
  __shared__ ushort Bb[2][16384];   // B tile per step: 256 rows x 64 ushort

  const int tid = threadIdx.x;
  const int bid = blockIdx.x;
  // bijective XCD swizzle (256 blocks): 4 n-panels x 8 ks per XCD
  const int l  = (bid & 7) * 32 + (bid >> 3);
  const int nb = l >> 3;              // 0..31
  const int ks = l & 7;
  const int n0 = nb * BN;
  const int ks8 = ks * 4;             // first superblock of this k-slice

  const int lane = tid & 63;
  const int wave = tid >> 6;          // 0..7
  const int wn   = (wave & 1) * 128;  // n-half
  const int wmg  = (wave >> 1);       // m-group 0..3 (64 rows each)
  const int brow = lane & 31;
  const int bco  = lane >> 5;

  const int sr = tid >> 1;            // dequant row 0..255
  const int sq = tid & 1;             // 16-int half of the 32-int qs group
  const int* bq0 = qw + (n0 + sr) * (KB * 144);

  uintx4 qA[4], qB[4];                // qs ring, 2 steps deep (16 ints each)
  floatx16 acc[2][4] = {};

  // meta slots (row sr only)
  float dA_, dmA_, dB_, dmB_;
  uintx4 mA0, mA1, mA2, mB0, mB1, mB2;

  auto gloadB = [&](int t, uintx4 (&Q)[4]) {
    const int* qp = bq0 + (ks8 + (t >> 2)) * 144 + 16 + (t & 3) * 32 + sq * 16;
    Q[0] = gld<uintx4>(qp);
    Q[1] = gld<uintx4>(qp + 4);
    Q[2] = gld<uintx4>(qp + 8);
    Q[3] = gld<uintx4>(qp + 12);
  };

  auto mloadA = [&](int sbrel) {
    const int* bp = bq0 + (ks8 + sbrel) * 144;
    const uintx4 dd = gld<uintx4>(bp);
    mA0 = gld<uintx4>(bp + 4); mA1 = gld<uintx4>(bp + 8); mA2 = gld<uintx4>(bp + 12);
    dA_  = __half2float(__ushort_as_half((ushort)((dd.x & 255u) | ((dd.y & 255u) << 8))));
    dmA_ = __half2float(__ushort_as_half((ushort)((dd.z & 255u) | ((dd.w & 255u) << 8))));
  };
  auto mloadB = [&](int sbrel) {
    const int* bp = bq0 + (ks8 + sbrel) * 144;
    const uintx4 dd = gld<uintx4>(bp);
    mB0 = gld<uintx4>(bp + 4); mB1 = gld<uintx4>(bp + 8); mB2 = gld<uintx4>(bp + 12);
    dB_  = __half2float(__ushort_as_half((ushort)((dd.x & 255u) | ((dd.y & 255u) << 8))));
    dmB_ = __half2float(__ushort_as_half((ushort)((dd.z & 255u) | ((dd.w & 255u) << 8))));
  };

  // A tile stage, PRE: 4 DMA per thread-wave issue (32 frags of 1KB)
  auto stageA = [&](int t, int slot) {
    #pragma unroll
    for (int q = 0; q < 4; ++q) {
      const int f = q * 8 + wave;               // frag id: mb = f>>2, kk = f&3
      const bf16x8* src = xbf + ((f >> 2) * 512 + ks * 64 + t * 4 + (f & 3)) * 64 + lane;
      glds16((const void*)src, (void*)&Al[slot][f * 512]);
    }
  };
  // A tile stage fallback: f32 -> bf16 cvt in regs -> ds_write
  auto stageAf = [&](int t, int slot) {
    #pragma unroll
    for (int j = 0; j < 4; ++j) {
      const int ls = tid * 4 + j;               // 0..2047
      const int f = ls >> 6, ll = ls & 63;
      const int m = (f >> 2) * 32 + (ll & 31);
      const int k = ks * KS + t * 64 + (f & 3) * 16 + (ll >> 5) * 8;
      const floatx4 a = gld<floatx4>(x + m * Kdim + k);
      const floatx4 b = gld<floatx4>(x + m * Kdim + k + 4);
      U8 u;
      u.u[0] = cvtpk(a.x, a.y); u.u[1] = cvtpk(a.z, a.w);
      u.u[2] = cvtpk(b.x, b.y); u.u[3] = cvtpk(b.z, b.w);
      *(bf16x8*)&Al[slot][ls * 8] = u.v;
    }
  };

  // dequant step t (c = t&3): row sr, 16 qs ints -> 32 lo + 32 hi weights
  auto dequant = [&](int c, const uintx4 (&Q)[4], bool useB, int buf) {
    const float d = useB ? dB_ : dA_, dm = useB ? dmB_ : dmA_;
    const uintx4 s0 = useB ? mB0 : mA0;
    const uintx4 s1 = useB ? mB1 : mA1;
    const uintx4 s2 = useB ? mB2 : mA2;
    uint scA, scB, mnA, mnB;
    if (c == 0)      { scA = s0.x & 63u; scB = s0.y & 63u; mnA = s1.x & 63u; mnB = s1.y & 63u; }
    else if (c == 1) { scA = s0.z & 63u; scB = s0.w & 63u; mnA = s1.z & 63u; mnB = s1.w & 63u; }
    else if (c == 2) {
      scA = (s2.x & 15u) | ((s0.x >> 2) & 48u); scB = (s2.y & 15u) | ((s0.y >> 2) & 48u);
      mnA = (s2.x >> 4)  | ((s1.x >> 2) & 48u); mnB = (s2.y >> 4)  | ((s1.y >> 2) & 48u);
    } else {
      scA = (s2.z & 15u) | ((s0.z >> 2) & 48u); scB = (s2.w & 15u) | ((s0.w >> 2) & 48u);
      mnA = (s2.z >> 4)  | ((s1.z >> 2) & 48u); mnB = (s2.w >> 4)  | ((s1.w >> 2) & 48u);
    }
    const float dlA = d * (float)scA, mlA = dm * (float)mnA;
    const float dlB = d * (float)scB, mlB = dm * (float)mnB;
    float wl[16], wh[16];
    #pragma unroll
    for (int g = 0; g < 4; ++g) {
      const uintx4 qv = Q[g];
      wl[g*4+0] = fmaf(dlA, (float)(qv.x & 15u), -mlA);
      wl[g*4+1] = fmaf(dlA, (float)(qv.y & 15u), -mlA);
      wl[g*4+2] = fmaf(dlA, (float)(qv.z & 15u), -mlA);
      wl[g*4+3] = fmaf(dlA, (float)(qv.w & 15u), -mlA);
      wh[g*4+0] = fmaf(dlB, (float)(qv.x >> 4), -mlB);
      wh[g*4+1] = fmaf(dlB, (float)(qv.y >> 4), -mlB);
      wh[g*4+2] = fmaf(dlB, (float)(qv.z >> 4), -mlB);
      wh[g*4+3] = fmaf(dlB, (float)(qv.w >> 4), -mlB);
    }
    U8 L0, L1, H0, H1;
    #pragma unroll
    for (int p = 0; p < 4; ++p) {
      L0.u[p] = cvtpk(wl[2*p],     wl[2*p+1]);
      L1.u[p] = cvtpk(wl[8+2*p],   wl[9+2*p]);
      H0.u[p] = cvtpk(wh[2*p],     wh[2*p+1]);
      H1.u[p] = cvtpk(wh[8+2*p],   wh[9+2*p]);
    }
    // lo nibbles -> k chunks sq*2, sq*2+1; hi -> 4+sq*2, 5+sq*2
    *(bf16x8*)&Bb[buf][bswz(sr, sq * 2)]     = L0.v;
    *(bf16x8*)&Bb[buf][bswz(sr, sq * 2 + 1)] = L1.v;
    *(bf16x8*)&Bb[buf][bswz(sr, 4 + sq * 2)] = H0.v;
    *(bf16x8*)&Bb[buf][bswz(sr, 5 + sq * 2)] = H1.v;
  };

  auto mstep = [&](int buf) {
    #pragma unroll
    for (int kk = 0; kk < 4; ++kk) {
      const bf16x8 af0 = *(const bf16x8*)&Al[buf][((wmg * 2    ) * 4 + kk) * 512 + lane * 8];
      const bf16x8 af1 = *(const bf16x8*)&Al[buf][((wmg * 2 + 1) * 4 + kk) * 512 + lane * 8];
      #pragma unroll
      for (int nf = 0; nf < 4; ++nf) {
        const bf16x8 bq = *(const bf16x8*)&Bb[buf][bswz(wn + nf * 32 + brow, kk * 2 + bco)];
        acc[0][nf] = __builtin_amdgcn_mfma_f32_32x32x16_bf16(af0, bq, acc[0][nf], 0, 0, 0);
        acc[1][nf] = __builtin_amdgcn_mfma_f32_32x32x16_bf16(af1, bq, acc[1][nf], 0, 0, 0);
      }
    }
  };

  // ---------------- prologue ----------------
  if constexpr (PRE) stageA(0, 0); else stageAf(0, 0);
  __builtin_amdgcn_sched_barrier(0);
  gloadB(0, qA);
  gloadB(1, qB);
  mloadA(0);
  dequant(0, qA, false, 0);
  if constexpr (PRE) { WAITVM(12); }       // certify A(0): 4+4+4 issued after
  asm volatile("s_waitcnt lgkmcnt(0)" ::: "memory");
  __builtin_amdgcn_s_barrier();
  __builtin_amdgcn_sched_barrier(0);

  // phase S: stage A(S+1); qs gld(S+2); meta(S in 1,5,9); dequant(S+1)->B[(S+1)&1];
  // mstep(S) from Al[S&1], Bb[S&1]; counted vmcnt certifies A(S+1); lgkm; barrier.
  #define PH(S, NVM) {                                                       \
    if ((S) + 1 < NT) { if constexpr (PRE) stageA((S)+1, ((S)+1)&1);         \
                        else stageAf((S)+1, ((S)+1)&1); }                    \
    __builtin_amdgcn_sched_barrier(0);                                       \
    if ((S) + 2 < NT) gloadB((S)+2, (((S)&1) ? qB : qA));                    \
    if ((S) == 1) mloadB(1);                                                 \
    if ((S) == 5) mloadA(2);                                                 \
    if ((S) == 9) mloadB(3);                                                 \
    if ((S) + 1 < NT)                                                        \
      dequant(((S)+1) & 3, ((((S)+1)&1) ? qB : qA),                          \
              (((((S)+1) >> 2) & 1) != 0), ((S)+1)&1);                       \
    __builtin_amdgcn_s_setprio(1);                                           \
    mstep((S)&1);                                                            \
    __builtin_amdgcn_s_setprio(0);                                           \
    if constexpr (PRE) { if ((S) + 1 < NT) { NVM; } }                        \
    asm volatile("s_waitcnt lgkmcnt(0)" ::: "memory");                       \
    __builtin_amdgcn_s_barrier();                                            \
    __builtin_amdgcn_sched_barrier(0);                                       \
  }

  PH(0,  WAITVM(4))
  PH(1,  WAITVM(8))
  PH(2,  WAITVM(4)) PH(3,  WAITVM(4)) PH(4,  WAITVM(4))
  PH(5,  WAITVM(8))
  PH(6,  WAITVM(4)) PH(7,  WAITVM(4)) PH(8,  WAITVM(4))
  PH(9,  WAITVM(8))
  PH(10, WAITVM(4)) PH(11, WAITVM(4)) PH(12, WAITVM(4)) PH(13, WAITVM(4))
  PH(14, WAITVM(0))
  PH(15, WAITVM(0))
  #undef PH

  // epilogue: D layout col=lane&31, row=(r&3)+8*(r>>2)+4*(lane>>5)  [m74/m101]
  const int mbase = wmg * 64 + 4 * (lane >> 5);
  #pragma unroll
  for (int nf = 0; nf < 4; ++nf) {
    const int gn = n0 + wn + nf * 32 + (lane & 31);
    const float bv = (ks == 0) ? bias[gn] : 0.0f;
    #pragma unroll
    for (int mf = 0; mf < 2; ++mf) {
      #pragma unroll
      for (int r = 0; r < 16; ++r) {
        const int m = mbase + mf * 32 + (r & 3) + 8 * (r >> 2);
        atomicAdd(&out[m * Ndim + gn], acc[mf][nf][r] + bv);
      }
    }
  }
}

// zero d_out (atomic accumulate target) and optionally pre-tile x -> bf16
// MFMA-fragment layout: xb[(mb*512+kb)*64+lane], m = mb*32+(lane&31),
// k = kb*16+(lane>>5)*8
template<bool DOCVT>
__global__ __launch_bounds__(256)
void prep(const float* __restrict__ x, uintx4* __restrict__ xb,
          floatx4* __restrict__ out)
{
  const int gid = blockIdx.x * 256 + threadIdx.x;
  out[gid * 2]     = floatx4{0.f, 0.f, 0.f, 0.f};
  out[gid * 2 + 1] = floatx4{0.f, 0.f, 0.f, 0.f};
  if (DOCVT) {
    const int lane = gid & 63;
    const int m = ((gid >> 15) * 32) + (lane & 31);
    const int k = (((gid >> 6) & 511) * 16) + (lane >> 5) * 8;
    const floatx4 f0 = gld<floatx4>(x + m * Kdim + k);
    const floatx4 f1 = gld<floatx4>(x + m * Kdim + k + 4);
    uintx4 st;
    st.x = cvtpk(f0.x, f0.y); st.y = cvtpk(f0.z, f0.w);
    st.z = cvtpk(f1.x, f1.y); st.w = cvtpk(f1.z, f1.w);
    xb[gid] = st;
  }
}

extern "C" void kernel_launch(void* const* d_in, const int* in_sizes, int n_in,
                              void* d_out, int out_size, void* d_ws, size_t ws_size,
                              hipStream_t stream) {
  (void)in_sizes; (void)n_in; (void)out_size;
  const float* x    = (const float*)d_in[0];
  const int*   qw   = (const int*)d_in[1];
  const float* bias = (const float*)d_in[2];
  float* out = (float*)d_out;

  const size_t need = (size_t)Mdim * Kdim * 2;   // 4 MB bf16 fragment tiles
  if (ws_size >= need) {
    prep<true><<<1024, 256, 0, stream>>>(x, (uintx4*)d_ws, (floatx4*)out);
    q4k_gemm<true><<<256, 512, 0, stream>>>(x, (const bf16x8*)d_ws, qw, bias, out);
  } else {
    prep<false><<<1024, 256, 0, stream>>>(x, nullptr, (floatx4*)out);
    q4k_gemm<false><<<256, 512, 0, stream>>>(x, nullptr, qw, bias, out);
  }
}

// Round 13
// 61.402 us; speedup vs baseline: 1.6460x; 1.6460x over previous
//
#include <hip/hip_runtime.h>
#include <hip/hip_fp16.h>

typedef __bf16 bf16x8 __attribute__((ext_vector_type(8)));
typedef float floatx16 __attribute__((ext_vector_type(16)));
typedef unsigned int uint;
typedef unsigned short ushort;
typedef uint  uintx4  __attribute__((ext_vector_type(4)));
typedef float floatx4 __attribute__((ext_vector_type(4)));

constexpr int Mdim = 256, Ndim = 8192, Kdim = 8192;
constexpr int BN = 64, KSPLIT = 4;
constexpr int KS = Kdim / KSPLIT;    // 2048 k per block
constexpr int NT = KS / 64;          // 32 64k-steps (2 per barrier phase)
constexpr int KB = Kdim / 256;       // 32 superblocks per weight row

union U8 { uint u[4]; bf16x8 v; };

__device__ __forceinline__ uint cvtpk(float lo, float hi) {
  uint r; asm("v_cvt_pk_bf16_f32 %0, %1, %2" : "=v"(r) : "v"(lo), "v"(hi));
  return r;
}

// explicit global (addrspace(1)) loads: guaranteed global_load_* (vmcnt-only)
template <typename T>
__device__ __forceinline__ T gld(const void* p) {
  return *(const __attribute__((address_space(1))) T*)p;
}

// B LDS: 64 rows x 128 ushort (256B row); 16 chunks of 16B, XOR-swizzled
__device__ __forceinline__ int bswz(int row, int ch) {
  return row * 128 + ((ch ^ (row & 15)) << 3);
}

template<bool PRE, bool PART>
__global__ __launch_bounds__(256, 2)
void q4k_gemm(const float* __restrict__ x, const bf16x8* __restrict__ xbf,
              const int* __restrict__ qw, const float* __restrict__ bias,
              float* __restrict__ out, float* __restrict__ pout)
{
  __shared__ ushort Bb[2][BN * 128];   // 16 KB each, double-buffered

  const int tid = threadIdx.x;
  const int bid = blockIdx.x;
  // bijective XCD swizzle (512 blocks): ks-siblings of one n-tile co-XCD
  const int l  = (bid & 7) * 64 + (bid >> 3);
  const int nb = l >> 2;              // 0..127
  const int ks = l & 3;
  const int n0 = nb * BN;
  const int ks8 = ks * (KS >> 8);

  const int sr = tid >> 2;   // B staging row 0..63
  const int sq = tid & 3;    // 8-int slice within the 32-int qs group

  const int lane = tid & 63;
  const int wave = tid >> 6;
  const int mb0  = wave * 2;          // two 32-row m-frags per wave
  const int brow = lane & 31;
  const int bco  = lane >> 5;

  const int* bp0 = qw + (n0 + sr) * (KB * 144);
  const bf16x8* xA0 = PRE ? (xbf + ((mb0    ) * 512 + ks * 128) * 64 + lane) : nullptr;
  const bf16x8* xA1 = PRE ? (xbf + ((mb0 + 1) * 512 + ks * 128) * 64 + lane) : nullptr;

  uintx4 R[4][2];                        // qs ring: 4 steps deep
  uintx4 Mdd[2], M0[2], M1[2], M2[2];    // meta: 2 superblock slots
  U8 pqL, pqH;
  bf16x8 aA[8], aB[8];
  floatx16 acc00 = {}, acc01 = {}, acc10 = {}, acc11 = {};

  auto gloadB = [&](int s2, int rs) {
    const int* qp = bp0 + (ks8 + (s2 >> 2)) * 144 + 16 + (s2 & 3) * 32 + sq * 8;
    R[rs][0] = gld<uintx4>(qp);
    R[rs][1] = gld<uintx4>(qp + 4);
  };

  auto mload = [&](int sbrel, int ms) {
    const int* bp = bp0 + (ks8 + sbrel) * 144;
    Mdd[ms] = gld<uintx4>(bp);
    M0[ms]  = gld<uintx4>(bp + 4);
    M1[ms]  = gld<uintx4>(bp + 8);
    M2[ms]  = gld<uintx4>(bp + 12);
  };

  auto gloadA = [&](int t, bf16x8 (&A)[8]) {
    if constexpr (PRE) {
      const int f = t * 4 * 64;
      #pragma unroll
      for (int kk = 0; kk < 4; ++kk) {
        A[kk]     = gld<bf16x8>(xA0 + f + kk * 64);
        A[4 + kk] = gld<bf16x8>(xA1 + f + kk * 64);
      }
    } else {
      const int kg = ks * KS + t * 64 + bco * 8;
      #pragma unroll
      for (int kk = 0; kk < 4; ++kk) {
        const float* fA = x + (mb0 * 32 + brow) * Kdim + kg + kk * 16;
        const float* fB = x + ((mb0 + 1) * 32 + brow) * Kdim + kg + kk * 16;
        const floatx4 p0 = gld<floatx4>(fA), p1 = gld<floatx4>(fA + 4);
        const floatx4 q0 = gld<floatx4>(fB), q1 = gld<floatx4>(fB + 4);
        U8 ua, ub;
        ua.u[0] = cvtpk(p0.x, p0.y); ua.u[1] = cvtpk(p0.z, p0.w);
        ua.u[2] = cvtpk(p1.x, p1.y); ua.u[3] = cvtpk(p1.z, p1.w);
        ub.u[0] = cvtpk(q0.x, q0.y); ub.u[1] = cvtpk(q0.z, q0.w);
        ub.u[2] = cvtpk(q1.x, q1.y); ub.u[3] = cvtpk(q1.z, q1.w);
        A[kk] = ua.v; A[4 + kk] = ub.v;
      }
    }
  };

  auto dequant = [&](int c, int rs, int ms) {
    const uintx4 dd = Mdd[ms];
    const float d  = __half2float(__ushort_as_half((ushort)((dd.x & 255u) | ((dd.y & 255u) << 8))));
    const float dm = __half2float(__ushort_as_half((ushort)((dd.z & 255u) | ((dd.w & 255u) << 8))));
    const uintx4 s0 = M0[ms], s1 = M1[ms], s2 = M2[ms];
    uint scA, scB, mnA, mnB;
    if (c == 0)      { scA = s0.x & 63u; scB = s0.y & 63u; mnA = s1.x & 63u; mnB = s1.y & 63u; }
    else if (c == 1) { scA = s0.z & 63u; scB = s0.w & 63u; mnA = s1.z & 63u; mnB = s1.w & 63u; }
    else if (c == 2) {
      scA = (s2.x & 15u) | ((s0.x >> 2) & 48u); scB = (s2.y & 15u) | ((s0.y >> 2) & 48u);
      mnA = (s2.x >> 4)  | ((s1.x >> 2) & 48u); mnB = (s2.y >> 4)  | ((s1.y >> 2) & 48u);
    } else {
      scA = (s2.z & 15u) | ((s0.z >> 2) & 48u); scB = (s2.w & 15u) | ((s0.w >> 2) & 48u);
      mnA = (s2.z >> 4)  | ((s1.z >> 2) & 48u); mnB = (s2.w >> 4)  | ((s1.w >> 2) & 48u);
    }
    const float dlA = d * (float)scA, mlA = dm * (float)mnA;
    const float dlB = d * (float)scB, mlB = dm * (float)mnB;
    float wl[8], wh[8];
    #pragma unroll
    for (int h = 0; h < 2; ++h) {
      const uintx4 qv = R[rs][h];
      wl[h*4+0] = fmaf(dlA, (float)(qv.x & 15u), -mlA);
      wl[h*4+1] = fmaf(dlA, (float)(qv.y & 15u), -mlA);
      wl[h*4+2] = fmaf(dlA, (float)(qv.z & 15u), -mlA);
      wl[h*4+3] = fmaf(dlA, (float)(qv.w & 15u), -mlA);
      wh[h*4+0] = fmaf(dlB, (float)(qv.x >> 4), -mlB);
      wh[h*4+1] = fmaf(dlB, (float)(qv.y >> 4), -mlB);
      wh[h*4+2] = fmaf(dlB, (float)(qv.z >> 4), -mlB);
      wh[h*4+3] = fmaf(dlB, (float)(qv.w >> 4), -mlB);
    }
    #pragma unroll
    for (int p = 0; p < 4; ++p) {
      pqL.u[p] = cvtpk(wl[2*p], wl[2*p+1]);
      pqH.u[p] = cvtpk(wh[2*p], wh[2*p+1]);
    }
  };

  auto bwrite = [&](int bufi, int h) {
    *(bf16x8*)&Bb[bufi][bswz(sr, h * 8 + sq)]     = pqL.v;
    *(bf16x8*)&Bb[bufi][bswz(sr, h * 8 + 4 + sq)] = pqH.v;
  };

  auto mstep = [&](int bufi, int h, const bf16x8 (&A)[8]) {
    #pragma unroll
    for (int kk = 0; kk < 4; ++kk) {
      const bf16x8 bq0 = *(const bf16x8*)&Bb[bufi][bswz(brow,      h * 8 + kk * 2 + bco)];
      const bf16x8 bq1 = *(const bf16x8*)&Bb[bufi][bswz(brow + 32, h * 8 + kk * 2 + bco)];
      acc00 = __builtin_amdgcn_mfma_f32_32x32x16_bf16(A[kk],     bq0, acc00, 0, 0, 0);
      acc01 = __builtin_amdgcn_mfma_f32_32x32x16_bf16(A[kk],     bq1, acc01, 0, 0, 0);
      acc10 = __builtin_amdgcn_mfma_f32_32x32x16_bf16(A[4 + kk], bq0, acc10, 0, 0, 0);
      acc11 = __builtin_amdgcn_mfma_f32_32x32x16_bf16(A[4 + kk], bq1, acc11, 0, 0, 0);
    }
  };

  // prologue: meta sb0/sb1; qs steps 0..3; A steps 0,1; stage buf0 (steps 0,1)
  mload(0, 0); mload(1, 1);
  gloadB(0, 0); gloadB(1, 1); gloadB(2, 2); gloadB(3, 3);
  gloadA(0, aA); gloadA(1, aB);
  dequant(0, 0, 0); bwrite(0, 0);
  dequant(1, 1, 0); bwrite(0, 1);
  asm volatile("s_waitcnt lgkmcnt(0)" ::: "memory");
  __builtin_amdgcn_s_barrier();
  __builtin_amdgcn_sched_barrier(0);

  #define MLOADJ(j)                                                          \
    if ((j) == 1) { const int sb_ = B / 2 + 2; if (sb_ < 8) mload(sb_, 0); } \
    else if ((j) == 3) { const int sb_ = B / 2 + 3; if (sb_ < 8) mload(sb_, 1); }

  #define PH2(j) {                                                           \
    const int p_ = B + (j);                                                  \
    const int s1_ = 2 * p_ + 2, s2_ = 2 * p_ + 3;                            \
    if (s1_ < NT) { dequant((2*(j)+2)&3, (2*(j)+2)&3, (((j)+1)>>1)&1);       \
                    bwrite(((j)&1)^1, 0); }                                  \
    if (s2_ < NT) { dequant((2*(j)+3)&3, (2*(j)+3)&3, (((j)+1)>>1)&1);       \
                    bwrite(((j)&1)^1, 1); }                                  \
    if (s1_ + 2 < NT) gloadB(s1_ + 2, (2*(j)+4)&3);                          \
    if (s2_ + 2 < NT) gloadB(s2_ + 2, (2*(j)+5)&3);                          \
    MLOADJ(j)                                                                \
    __builtin_amdgcn_s_setprio(1);                                           \
    mstep((j)&1, 0, aA);                                                     \
    __builtin_amdgcn_s_setprio(0);                                           \
    if (s1_ < NT) gloadA(s1_, aA);                                           \
    __builtin_amdgcn_s_setprio(1);                                           \
    mstep((j)&1, 1, aB);                                                     \
    __builtin_amdgcn_s_setprio(0);                                           \
    if (s2_ < NT) gloadA(s2_, aB);                                           \
    asm volatile("s_waitcnt lgkmcnt(0)" ::: "memory");                       \
    __builtin_amdgcn_s_barrier();                                            \
    __builtin_amdgcn_sched_barrier(0);                                       \
  }

  for (int i = 0; i < 4; ++i) {
    const int B = i * 4;
    PH2(0) PH2(1) PH2(2) PH2(3)
  }
  #undef PH2
  #undef MLOADJ

  // epilogue: D layout col=lane&31, row=(r&3)+8*(r>>2)+4*(lane>>5)  [m74/m101]
  const int gn0 = n0 + (lane & 31);
  const int gn1 = gn0 + 32;
  const int mrow = wave * 64 + 4 * (lane >> 5);
  if constexpr (PART) {
    float* pp = pout + (size_t)ks * ((size_t)Mdim * Ndim);
    #pragma unroll
    for (int r = 0; r < 16; ++r) {
      const int m = mrow + (r & 3) + 8 * (r >> 2);
      pp[m * Ndim + gn0] = acc00[r];
      pp[m * Ndim + gn1] = acc01[r];
      pp[(m + 32) * Ndim + gn0] = acc10[r];
      pp[(m + 32) * Ndim + gn1] = acc11[r];
    }
  } else {
    const float bv0 = (ks == 0) ? bias[gn0] : 0.0f;
    const float bv1 = (ks == 0) ? bias[gn1] : 0.0f;
    #pragma unroll
    for (int r = 0; r < 16; ++r) {
      const int m = mrow + (r & 3) + 8 * (r >> 2);
      atomicAdd(&out[m * Ndim + gn0], acc00[r] + bv0);
      atomicAdd(&out[m * Ndim + gn1], acc01[r] + bv1);
      atomicAdd(&out[(m + 32) * Ndim + gn0], acc10[r] + bv0);
      atomicAdd(&out[(m + 32) * Ndim + gn1], acc11[r] + bv1);
    }
  }
}

// sum 4 partial buffers + bias -> out (streaming, float4)
__global__ __launch_bounds__(256)
void reduce4(const floatx4* __restrict__ p, const float* __restrict__ bias,
             floatx4* __restrict__ out)
{
  const int gid = blockIdx.x * 256 + threadIdx.x;       // 524288 float4s
  constexpr int STR = (Mdim * Ndim) / 4;                // 524288
  floatx4 s = gld<floatx4>(p + gid);
  s += gld<floatx4>(p + gid + STR);
  s += gld<floatx4>(p + gid + 2 * STR);
  s += gld<floatx4>(p + gid + 3 * STR);
  s += gld<floatx4>((const floatx4*)bias + (gid & 2047));
  out[gid] = s;
}

// optionally zero d_out (atomic path) and optionally pre-tile x -> bf16
// MFMA-fragment layout: xb[(mb*512+kb)*64+lane], m = mb*32+(lane&31),
// k = kb*16+(lane>>5)*8
template<bool DOCVT, bool ZERO>
__global__ __launch_bounds__(256)
void prep(const float* __restrict__ x, uintx4* __restrict__ xb,
          floatx4* __restrict__ out)
{
  const int gid = blockIdx.x * 256 + threadIdx.x;
  if (ZERO) {
    out[gid * 2]     = floatx4{0.f, 0.f, 0.f, 0.f};
    out[gid * 2 + 1] = floatx4{0.f, 0.f, 0.f, 0.f};
  }
  if (DOCVT) {
    const int lane = gid & 63;
    const int m = ((gid >> 15) * 32) + (lane & 31);
    const int k = (((gid >> 6) & 511) * 16) + (lane >> 5) * 8;
    const floatx4 f0 = gld<floatx4>(x + m * Kdim + k);
    const floatx4 f1 = gld<floatx4>(x + m * Kdim + k + 4);
    uintx4 st;
    st.x = cvtpk(f0.x, f0.y); st.y = cvtpk(f0.z, f0.w);
    st.z = cvtpk(f1.x, f1.y); st.w = cvtpk(f1.z, f1.w);
    xb[gid] = st;
  }
}

extern "C" void kernel_launch(void* const* d_in, const int* in_sizes, int n_in,
                              void* d_out, int out_size, void* d_ws, size_t ws_size,
                              hipStream_t stream) {
  (void)in_sizes; (void)n_in; (void)out_size;
  const float* x    = (const float*)d_in[0];
  const int*   qw   = (const int*)d_in[1];
  const float* bias = (const float*)d_in[2];
  float* out = (float*)d_out;

  const size_t needXB   = (size_t)Mdim * Kdim * 2;                 // 4 MB
  const size_t needPART = needXB + (size_t)KSPLIT * Mdim * Ndim * 4; // +32 MB
  if (ws_size >= needPART) {
    float* part = (float*)((char*)d_ws + needXB);
    prep<true, false><<<1024, 256, 0, stream>>>(x, (uintx4*)d_ws, (floatx4*)out);
    q4k_gemm<true, true><<<512, 256, 0, stream>>>(
        x, (const bf16x8*)d_ws, qw, bias, out, part);
    reduce4<<<(Mdim * Ndim / 4) / 256, 256, 0, stream>>>(
        (const floatx4*)part, bias, (floatx4*)out);
  } else if (ws_size >= needXB) {
    prep<true, true><<<1024, 256, 0, stream>>>(x, (uintx4*)d_ws, (floatx4*)out);
    q4k_gemm<true, false><<<512, 256, 0, stream>>>(
        x, (const bf16x8*)d_ws, qw, bias, out, nullptr);
  } else {
    prep<false, true><<<1024, 256, 0, stream>>>(x, nullptr, (floatx4*)out);
    q4k_gemm<false, false><<<512, 256, 0, stream>>>(
        x, nullptr, qw, bias, out, nullptr);
  }
}

// Round 14
// 61.174 us; speedup vs baseline: 1.6521x; 1.0037x over previous
//
#include <hip/hip_runtime.h>
#include <hip/hip_fp16.h>

typedef __bf16 bf16x8 __attribute__((ext_vector_type(8)));
typedef float floatx16 __attribute__((ext_vector_type(16)));
typedef unsigned int uint;
typedef unsigned short ushort;
typedef uint  uintx4  __attribute__((ext_vector_type(4)));
typedef float floatx4 __attribute__((ext_vector_type(4)));

constexpr int Mdim = 256, Ndim = 8192, Kdim = 8192;
constexpr int BN = 128, KSPLIT = 4;
constexpr int KS = Kdim / KSPLIT;    // 2048 k per block
constexpr int NT = KS / 64;          // 32 64k-steps (2 per barrier phase)
constexpr int KB = Kdim / 256;       // 32 superblocks per weight row

union U8 { uint u[4]; bf16x8 v; };

__device__ __forceinline__ uint cvtpk(float lo, float hi) {
  uint r; asm("v_cvt_pk_bf16_f32 %0, %1, %2" : "=v"(r) : "v"(lo), "v"(hi));
  return r;
}

// explicit global (addrspace(1)) loads: guaranteed global_load_* (vmcnt-only)
template <typename T>
__device__ __forceinline__ T gld(const void* p) {
  return *(const __attribute__((address_space(1))) T*)p;
}

// B LDS: 128 rows x 128 ushort (256B row); 16 chunks of 16B, XOR-swizzled
__device__ __forceinline__ int bswz(int row, int ch) {
  return row * 128 + ((ch ^ (row & 15)) << 3);
}

template<bool PRE, bool PART>
__global__ __launch_bounds__(512, 1)
void q4k_gemm(const float* __restrict__ x, const bf16x8* __restrict__ xbf,
              const int* __restrict__ qw, const float* __restrict__ bias,
              float* __restrict__ out, float* __restrict__ pout)
{
  __shared__ ushort Bb[2][BN * 128];   // 32 KB each, double-buffered

  const int tid = threadIdx.x;
  const int bid = blockIdx.x;
  // bijective XCD swizzle (256 blocks): ks-siblings of one n-tile co-XCD
  const int l  = (bid & 7) * 32 + (bid >> 3);
  const int nb = l >> 2;              // 0..63
  const int ks = l & 3;
  const int n0 = nb * BN;
  const int ks8 = ks * (KS >> 8);

  const int sr = tid >> 2;   // B staging row 0..127
  const int sq = tid & 3;    // 8-int slice within the 32-int qs group

  const int lane = tid & 63;
  const int wave = tid >> 6;          // 0..7
  const int wmg  = wave >> 1;         // m-group 0..3 (64 rows each)
  const int wn   = (wave & 1) * 64;   // n-half within the 128-col tile
  const int mb0  = wmg * 2;           // two 32-row m-frags per wave
  const int brow = lane & 31;
  const int bco  = lane >> 5;

  const int* bp0 = qw + (n0 + sr) * (KB * 144);
  const bf16x8* xA0 = PRE ? (xbf + ((mb0    ) * 512 + ks * 128) * 64 + lane) : nullptr;
  const bf16x8* xA1 = PRE ? (xbf + ((mb0 + 1) * 512 + ks * 128) * 64 + lane) : nullptr;

  uintx4 R[4][2];                        // qs ring: 4 steps deep
  uintx4 Mdd[2], M0[2], M1[2], M2[2];    // meta: 2 superblock slots
  U8 pqL, pqH;
  bf16x8 aA[8], aB[8];
  floatx16 acc00 = {}, acc01 = {}, acc10 = {}, acc11 = {};

  auto gloadB = [&](int s2, int rs) {
    const int* qp = bp0 + (ks8 + (s2 >> 2)) * 144 + 16 + (s2 & 3) * 32 + sq * 8;
    R[rs][0] = gld<uintx4>(qp);
    R[rs][1] = gld<uintx4>(qp + 4);
  };

  auto mload = [&](int sbrel, int ms) {
    const int* bp = bp0 + (ks8 + sbrel) * 144;
    Mdd[ms] = gld<uintx4>(bp);
    M0[ms]  = gld<uintx4>(bp + 4);
    M1[ms]  = gld<uintx4>(bp + 8);
    M2[ms]  = gld<uintx4>(bp + 12);
  };

  auto gloadA = [&](int t, bf16x8 (&A)[8]) {
    if constexpr (PRE) {
      const int f = t * 4 * 64;
      #pragma unroll
      for (int kk = 0; kk < 4; ++kk) {
        A[kk]     = gld<bf16x8>(xA0 + f + kk * 64);
        A[4 + kk] = gld<bf16x8>(xA1 + f + kk * 64);
      }
    } else {
      const int kg = ks * KS + t * 64 + bco * 8;
      #pragma unroll
      for (int kk = 0; kk < 4; ++kk) {
        const float* fA = x + (mb0 * 32 + brow) * Kdim + kg + kk * 16;
        const float* fB = x + ((mb0 + 1) * 32 + brow) * Kdim + kg + kk * 16;
        const floatx4 p0 = gld<floatx4>(fA), p1 = gld<floatx4>(fA + 4);
        const floatx4 q0 = gld<floatx4>(fB), q1 = gld<floatx4>(fB + 4);
        U8 ua, ub;
        ua.u[0] = cvtpk(p0.x, p0.y); ua.u[1] = cvtpk(p0.z, p0.w);
        ua.u[2] = cvtpk(p1.x, p1.y); ua.u[3] = cvtpk(p1.z, p1.w);
        ub.u[0] = cvtpk(q0.x, q0.y); ub.u[1] = cvtpk(q0.z, q0.w);
        ub.u[2] = cvtpk(q1.x, q1.y); ub.u[3] = cvtpk(q1.z, q1.w);
        A[kk] = ua.v; A[4 + kk] = ub.v;
      }
    }
  };

  auto dequant = [&](int c, int rs, int ms) {
    const uintx4 dd = Mdd[ms];
    const float d  = __half2float(__ushort_as_half((ushort)((dd.x & 255u) | ((dd.y & 255u) << 8))));
    const float dm = __half2float(__ushort_as_half((ushort)((dd.z & 255u) | ((dd.w & 255u) << 8))));
    const uintx4 s0 = M0[ms], s1 = M1[ms], s2 = M2[ms];
    uint scA, scB, mnA, mnB;
    if (c == 0)      { scA = s0.x & 63u; scB = s0.y & 63u; mnA = s1.x & 63u; mnB = s1.y & 63u; }
    else if (c == 1) { scA = s0.z & 63u; scB = s0.w & 63u; mnA = s1.z & 63u; mnB = s1.w & 63u; }
    else if (c == 2) {
      scA = (s2.x & 15u) | ((s0.x >> 2) & 48u); scB = (s2.y & 15u) | ((s0.y >> 2) & 48u);
      mnA = (s2.x >> 4)  | ((s1.x >> 2) & 48u); mnB = (s2.y >> 4)  | ((s1.y >> 2) & 48u);
    } else {
      scA = (s2.z & 15u) | ((s0.z >> 2) & 48u); scB = (s2.w & 15u) | ((s0.w >> 2) & 48u);
      mnA = (s2.z >> 4)  | ((s1.z >> 2) & 48u); mnB = (s2.w >> 4)  | ((s1.w >> 2) & 48u);
    }
    const float dlA = d * (float)scA, mlA = dm * (float)mnA;
    const float dlB = d * (float)scB, mlB = dm * (float)mnB;
    float wl[8], wh[8];
    #pragma unroll
    for (int h = 0; h < 2; ++h) {
      const uintx4 qv = R[rs][h];
      wl[h*4+0] = fmaf(dlA, (float)(qv.x & 15u), -mlA);
      wl[h*4+1] = fmaf(dlA, (float)(qv.y & 15u), -mlA);
      wl[h*4+2] = fmaf(dlA, (float)(qv.z & 15u), -mlA);
      wl[h*4+3] = fmaf(dlA, (float)(qv.w & 15u), -mlA);
      wh[h*4+0] = fmaf(dlB, (float)(qv.x >> 4), -mlB);
      wh[h*4+1] = fmaf(dlB, (float)(qv.y >> 4), -mlB);
      wh[h*4+2] = fmaf(dlB, (float)(qv.z >> 4), -mlB);
      wh[h*4+3] = fmaf(dlB, (float)(qv.w >> 4), -mlB);
    }
    #pragma unroll
    for (int p = 0; p < 4; ++p) {
      pqL.u[p] = cvtpk(wl[2*p], wl[2*p+1]);
      pqH.u[p] = cvtpk(wh[2*p], wh[2*p+1]);
    }
  };

  auto bwrite = [&](int bufi, int h) {
    *(bf16x8*)&Bb[bufi][bswz(sr, h * 8 + sq)]     = pqL.v;
    *(bf16x8*)&Bb[bufi][bswz(sr, h * 8 + 4 + sq)] = pqH.v;
  };

  auto mstep = [&](int bufi, int h, const bf16x8 (&A)[8]) {
    #pragma unroll
    for (int kk = 0; kk < 4; ++kk) {
      const bf16x8 bq0 = *(const bf16x8*)&Bb[bufi][bswz(wn + brow,      h * 8 + kk * 2 + bco)];
      const bf16x8 bq1 = *(const bf16x8*)&Bb[bufi][bswz(wn + brow + 32, h * 8 + kk * 2 + bco)];
      acc00 = __builtin_amdgcn_mfma_f32_32x32x16_bf16(A[kk],     bq0, acc00, 0, 0, 0);
      acc01 = __builtin_amdgcn_mfma_f32_32x32x16_bf16(A[kk],     bq1, acc01, 0, 0, 0);
      acc10 = __builtin_amdgcn_mfma_f32_32x32x16_bf16(A[4 + kk], bq0, acc10, 0, 0, 0);
      acc11 = __builtin_amdgcn_mfma_f32_32x32x16_bf16(A[4 + kk], bq1, acc11, 0, 0, 0);
    }
  };

  // prologue: meta sb0/sb1; qs steps 0..3; A steps 0,1; stage buf0 (steps 0,1)
  mload(0, 0); mload(1, 1);
  gloadB(0, 0); gloadB(1, 1); gloadB(2, 2); gloadB(3, 3);
  gloadA(0, aA); gloadA(1, aB);
  dequant(0, 0, 0); bwrite(0, 0);
  dequant(1, 1, 0); bwrite(0, 1);
  asm volatile("s_waitcnt lgkmcnt(0)" ::: "memory");
  __builtin_amdgcn_s_barrier();
  __builtin_amdgcn_sched_barrier(0);

  #define MLOADJ(j)                                                          \
    if ((j) == 1) { const int sb_ = B / 2 + 2; if (sb_ < 8) mload(sb_, 0); } \
    else if ((j) == 3) { const int sb_ = B / 2 + 3; if (sb_ < 8) mload(sb_, 1); }

  #define PH2(j) {                                                           \
    const int p_ = B + (j);                                                  \
    const int s1_ = 2 * p_ + 2, s2_ = 2 * p_ + 3;                            \
    if (s1_ < NT) { dequant((2*(j)+2)&3, (2*(j)+2)&3, (((j)+1)>>1)&1);       \
                    bwrite(((j)&1)^1, 0); }                                  \
    if (s2_ < NT) { dequant((2*(j)+3)&3, (2*(j)+3)&3, (((j)+1)>>1)&1);       \
                    bwrite(((j)&1)^1, 1); }                                  \
    if (s1_ + 2 < NT) gloadB(s1_ + 2, (2*(j)+4)&3);                          \
    if (s2_ + 2 < NT) gloadB(s2_ + 2, (2*(j)+5)&3);                          \
    MLOADJ(j)                                                                \
    __builtin_amdgcn_s_setprio(1);                                           \
    mstep((j)&1, 0, aA);                                                     \
    __builtin_amdgcn_s_setprio(0);                                           \
    if (s1_ < NT) gloadA(s1_, aA);                                           \
    __builtin_amdgcn_s_setprio(1);                                           \
    mstep((j)&1, 1, aB);                                                     \
    __builtin_amdgcn_s_setprio(0);                                           \
    if (s2_ < NT) gloadA(s2_, aB);                                           \
    asm volatile("s_waitcnt lgkmcnt(0)" ::: "memory");                       \
    __builtin_amdgcn_s_barrier();                                            \
    __builtin_amdgcn_sched_barrier(0);                                       \
  }

  for (int i = 0; i < 4; ++i) {
    const int B = i * 4;
    PH2(0) PH2(1) PH2(2) PH2(3)
  }
  #undef PH2
  #undef MLOADJ

  // epilogue: D layout col=lane&31, row=(r&3)+8*(r>>2)+4*(lane>>5)  [m74/m101]
  const int gn0 = n0 + wn + (lane & 31);
  const int gn1 = gn0 + 32;
  const int mrow = wmg * 64 + 4 * (lane >> 5);
  if constexpr (PART) {
    float* pp = pout + (size_t)ks * ((size_t)Mdim * Ndim);
    #pragma unroll
    for (int r = 0; r < 16; ++r) {
      const int m = mrow + (r & 3) + 8 * (r >> 2);
      pp[m * Ndim + gn0] = acc00[r];
      pp[m * Ndim + gn1] = acc01[r];
      pp[(m + 32) * Ndim + gn0] = acc10[r];
      pp[(m + 32) * Ndim + gn1] = acc11[r];
    }
  } else {
    const float bv0 = (ks == 0) ? bias[gn0] : 0.0f;
    const float bv1 = (ks == 0) ? bias[gn1] : 0.0f;
    #pragma unroll
    for (int r = 0; r < 16; ++r) {
      const int m = mrow + (r & 3) + 8 * (r >> 2);
      atomicAdd(&out[m * Ndim + gn0], acc00[r] + bv0);
      atomicAdd(&out[m * Ndim + gn1], acc01[r] + bv1);
      atomicAdd(&out[(m + 32) * Ndim + gn0], acc10[r] + bv0);
      atomicAdd(&out[(m + 32) * Ndim + gn1], acc11[r] + bv1);
    }
  }
}

// sum 4 partial buffers + bias -> out (streaming, float4)
__global__ __launch_bounds__(256)
void reduce4(const floatx4* __restrict__ p, const float* __restrict__ bias,
             floatx4* __restrict__ out)
{
  const int gid = blockIdx.x * 256 + threadIdx.x;       // 524288 float4s
  constexpr int STR = (Mdim * Ndim) / 4;                // 524288
  floatx4 s = gld<floatx4>(p + gid);
  s += gld<floatx4>(p + gid + STR);
  s += gld<floatx4>(p + gid + 2 * STR);
  s += gld<floatx4>(p + gid + 3 * STR);
  s += gld<floatx4>((const floatx4*)bias + (gid & 2047));
  out[gid] = s;
}

// optionally zero d_out (atomic path) and optionally pre-tile x -> bf16
// MFMA-fragment layout: xb[(mb*512+kb)*64+lane], m = mb*32+(lane&31),
// k = kb*16+(lane>>5)*8
template<bool DOCVT, bool ZERO>
__global__ __launch_bounds__(256)
void prep(const float* __restrict__ x, uintx4* __restrict__ xb,
          floatx4* __restrict__ out)
{
  const int gid = blockIdx.x * 256 + threadIdx.x;
  if (ZERO) {
    out[gid * 2]     = floatx4{0.f, 0.f, 0.f, 0.f};
    out[gid * 2 + 1] = floatx4{0.f, 0.f, 0.f, 0.f};
  }
  if (DOCVT) {
    const int lane = gid & 63;
    const int m = ((gid >> 15) * 32) + (lane & 31);
    const int k = (((gid >> 6) & 511) * 16) + (lane >> 5) * 8;
    const floatx4 f0 = gld<floatx4>(x + m * Kdim + k);
    const floatx4 f1 = gld<floatx4>(x + m * Kdim + k + 4);
    uintx4 st;
    st.x = cvtpk(f0.x, f0.y); st.y = cvtpk(f0.z, f0.w);
    st.z = cvtpk(f1.x, f1.y); st.w = cvtpk(f1.z, f1.w);
    xb[gid] = st;
  }
}

extern "C" void kernel_launch(void* const* d_in, const int* in_sizes, int n_in,
                              void* d_out, int out_size, void* d_ws, size_t ws_size,
                              hipStream_t stream) {
  (void)in_sizes; (void)n_in; (void)out_size;
  const float* x    = (const float*)d_in[0];
  const int*   qw   = (const int*)d_in[1];
  const float* bias = (const float*)d_in[2];
  float* out = (float*)d_out;

  const size_t needXB   = (size_t)Mdim * Kdim * 2;                 // 4 MB
  const size_t needPART = needXB + (size_t)KSPLIT * Mdim * Ndim * 4; // +32 MB
  if (ws_size >= needPART) {
    float* part = (float*)((char*)d_ws + needXB);
    prep<true, false><<<1024, 256, 0, stream>>>(x, (uintx4*)d_ws, (floatx4*)out);
    q4k_gemm<true, true><<<256, 512, 0, stream>>>(
        x, (const bf16x8*)d_ws, qw, bias, out, part);
    reduce4<<<(Mdim * Ndim / 4) / 256, 256, 0, stream>>>(
        (const floatx4*)part, bias, (floatx4*)out);
  } else if (ws_size >= needXB) {
    prep<true, true><<<1024, 256, 0, stream>>>(x, (uintx4*)d_ws, (floatx4*)out);
    q4k_gemm<true, false><<<256, 512, 0, stream>>>(
        x, (const bf16x8*)d_ws, qw, bias, out, nullptr);
  } else {
    prep<false, true><<<1024, 256, 0, stream>>>(x, nullptr, (floatx4*)out);
    q4k_gemm<false, false><<<256, 512, 0, stream>>>(
        x, nullptr, qw, bias, out, nullptr);
  }
}